// Round 12
// baseline (1300.505 us; speedup 1.0000x reference)
//
#include <hip/hip_runtime.h>

#define USER_NUM 100000
#define ITEM_NUM 50000
#define NTOT     (USER_NUM + ITEM_NUM)
#define EMB      64
#define GAMMA    0.5f
#define NLAYERS  3
#define EPS      1e-12f

#define SCAN_CHUNK 256
#define NCHUNKS    ((NTOT + SCAN_CHUNK - 1) / SCAN_CHUNK)   // 586

#define COLBITS  18
#define COLMASK  ((1u << COLBITS) - 1u)
#define QMAX     16382.0f

// native clang vector types — __builtin_nontemporal_* requires these
typedef float fx4 __attribute__((ext_vector_type(4)));
typedef int   ix4 __attribute__((ext_vector_type(4)));

// ---- bf16 helpers (explicit RNE, bit-level) ----
__device__ __forceinline__ unsigned short f2bf(float f) {
    unsigned u = __float_as_uint(f);
    u = (u + 0x7FFFu + ((u >> 16) & 1u)) >> 16;
    return (unsigned short)u;
}
__device__ __forceinline__ float bf2f(unsigned short h) {
    return __uint_as_float((unsigned)h << 16);
}

// ===========================================================================
// init: Xh = bf16(normalize(concat(user,item))), out = GAMMA * concat(...)
// ===========================================================================
__global__ void init_kernel(const float* __restrict__ user_emb,
                            const float* __restrict__ item_emb,
                            unsigned short* __restrict__ Xh,
                            float* __restrict__ out) {
    int tid = blockIdx.x * blockDim.x + threadIdx.x;
    int row = tid >> 4;
    if (row >= NTOT) return;
    int l = tid & 15;
    const float* src = (row < USER_NUM)
        ? user_emb + (size_t)row * EMB
        : item_emb + (size_t)(row - USER_NUM) * EMB;
    fx4 v = *(reinterpret_cast<const fx4*>(src) + l);
    fx4 o = v * GAMMA;
    __builtin_nontemporal_store(o, reinterpret_cast<fx4*>(out) +
                                       ((size_t)row * 16 + l));
    float ss = v.x * v.x + v.y * v.y + v.z * v.z + v.w * v.w;
    ss += __shfl_xor(ss, 1);
    ss += __shfl_xor(ss, 2);
    ss += __shfl_xor(ss, 4);
    ss += __shfl_xor(ss, 8);
    float inv = 1.0f / (sqrtf(ss) + EPS);
    ushort4 h;
    h.x = f2bf(v.x * inv); h.y = f2bf(v.y * inv);
    h.z = f2bf(v.z * inv); h.w = f2bf(v.w * inv);
    reinterpret_cast<ushort4*>(Xh)[(size_t)row * 16 + l] = h;
}

// ===========================================================================
// vmax reduction (positive floats: int compare == float compare)
// ===========================================================================
__global__ void vmax_kernel(const float* __restrict__ vals,
                            int* __restrict__ vmax_bits, int nnz) {
    int tid = blockIdx.x * blockDim.x + threadIdx.x;
    int stride = gridDim.x * blockDim.x;
    int nnz4 = nnz >> 2;
    float m = 0.0f;
    for (int i = tid; i < nnz4; i += stride) {
        fx4 v = __builtin_nontemporal_load(
            reinterpret_cast<const fx4*>(vals) + i);
        m = fmaxf(m, fmaxf(fmaxf(v.x, v.y), fmaxf(v.z, v.w)));
    }
    if (tid == 0)
        for (int i = nnz4 << 2; i < nnz; ++i) m = fmaxf(m, vals[i]);
    m = fmaxf(m, __shfl_xor(m, 1));
    m = fmaxf(m, __shfl_xor(m, 2));
    m = fmaxf(m, __shfl_xor(m, 4));
    m = fmaxf(m, __shfl_xor(m, 8));
    m = fmaxf(m, __shfl_xor(m, 16));
    m = fmaxf(m, __shfl_xor(m, 32));
    if ((threadIdx.x & 63) == 0) atomicMax(vmax_bits, __float_as_int(m));
}

// ===========================================================================
// histogram (int4-vectorized, non-temporal index reads)
// ===========================================================================
__global__ void hist4_kernel(const int* __restrict__ rows,
                             int* __restrict__ counts, int nnz) {
    int tid = blockIdx.x * blockDim.x + threadIdx.x;
    int stride = gridDim.x * blockDim.x;
    int nnz4 = nnz >> 2;
    for (int i = tid; i < nnz4; i += stride) {
        ix4 r4 = __builtin_nontemporal_load(
            reinterpret_cast<const ix4*>(rows) + i);
        atomicAdd(&counts[r4.x], 1);
        atomicAdd(&counts[r4.y], 1);
        atomicAdd(&counts[r4.z], 1);
        atomicAdd(&counts[r4.w], 1);
    }
    if (tid == 0)
        for (int i = nnz4 << 2; i < nnz; ++i) atomicAdd(&counts[rows[i]], 1);
}

// ===========================================================================
// 3-step exclusive scan of per-row counts -> row_ptr (and cursor copy)
// ===========================================================================
__global__ void scan_sums_kernel(const int* __restrict__ counts,
                                 int* __restrict__ chunk_sums) {
    __shared__ int sdata[SCAN_CHUNK];
    int idx = blockIdx.x * SCAN_CHUNK + threadIdx.x;
    int v = (idx < NTOT) ? counts[idx] : 0;
    sdata[threadIdx.x] = v;
    __syncthreads();
    for (int off = SCAN_CHUNK / 2; off > 0; off >>= 1) {
        if (threadIdx.x < off) sdata[threadIdx.x] += sdata[threadIdx.x + off];
        __syncthreads();
    }
    if (threadIdx.x == 0) chunk_sums[blockIdx.x] = sdata[0];
}

__global__ void scan_offsets_kernel(int* __restrict__ chunk_sums,
                                    int* __restrict__ row_ptr) {
    if (threadIdx.x == 0 && blockIdx.x == 0) {
        int running = 0;
        for (int b = 0; b < NCHUNKS; ++b) {
            int t = chunk_sums[b];
            chunk_sums[b] = running;
            running += t;
        }
        row_ptr[NTOT] = running;
    }
}

__global__ void scan_write_kernel(const int* __restrict__ counts,
                                  const int* __restrict__ chunk_sums,
                                  int* __restrict__ row_ptr,
                                  int* __restrict__ cursor) {
    __shared__ int temp[SCAN_CHUNK];
    int idx = blockIdx.x * SCAN_CHUNK + threadIdx.x;
    int v = (idx < NTOT) ? counts[idx] : 0;
    temp[threadIdx.x] = v;
    __syncthreads();
    for (int off = 1; off < SCAN_CHUNK; off <<= 1) {
        int t = (threadIdx.x >= off) ? temp[threadIdx.x - off] : 0;
        __syncthreads();
        temp[threadIdx.x] += t;
        __syncthreads();
    }
    if (idx < NTOT) {
        int excl = temp[threadIdx.x] - v + chunk_sums[blockIdx.x];
        row_ptr[idx] = excl;
        cursor[idx]  = excl;
    }
}

// ===========================================================================
// window boundaries: rb[w] = smallest row with row_ptr[row] >= w*nnz/8.
// ===========================================================================
__global__ void winbounds_kernel(const int* __restrict__ row_ptr,
                                 int* __restrict__ rb, int nnz) {
    int w = threadIdx.x;
    if (w > 8) return;
    if (w == 0) { rb[0] = 0; return; }
    if (w == 8) { rb[8] = NTOT; return; }
    int target = (int)(((long long)nnz * w) >> 3);
    int lo = 0, hi = NTOT;
    while (lo < hi) {
        int mid = (lo + hi) >> 1;
        if (row_ptr[mid] < target) lo = mid + 1; else hi = mid;
    }
    rb[w] = lo;
}

// ===========================================================================
// XCD-cohort CSR build, 4-byte packed records, NON-TEMPORAL streaming reads:
// the read stream no longer allocates in L2, so the cohort's 4 MB cv window
// (+0.6 MB cursors) fits the XCD's 4 MB L2 and dirty lines accumulate all 16
// records before writeback.
// ===========================================================================
__global__ void build_xcd_kernel(const int* __restrict__ rows,
                                 const int* __restrict__ cols,
                                 const float* __restrict__ vals,
                                 int* __restrict__ cursor,
                                 const int* __restrict__ rb,
                                 const int* __restrict__ vmax_bits,
                                 unsigned* __restrict__ cv, int nnz) {
    __shared__ int srb[8];
    if (threadIdx.x < 8) srb[threadIdx.x] = rb[threadIdx.x];
    __syncthreads();
    const int b1 = srb[1], b2 = srb[2], b3 = srb[3], b4 = srb[4];
    const int b5 = srb[5], b6 = srb[6], b7 = srb[7];
    const int win = blockIdx.x & 7;
    float vmax = __int_as_float(__builtin_amdgcn_readfirstlane(*vmax_bits));
    float s = (vmax > 0.0f) ? (QMAX / vmax) : 0.0f;

    int i4      = (blockIdx.x >> 3) * blockDim.x + threadIdx.x;
    int stride4 = (gridDim.x >> 3) * blockDim.x;
    int nnz4    = nnz >> 2;
    for (; i4 < nnz4; i4 += stride4) {
        ix4 r4 = __builtin_nontemporal_load(
            reinterpret_cast<const ix4*>(rows) + i4);
        int rr[4] = {r4.x, r4.y, r4.z, r4.w};
#pragma unroll
        for (int j = 0; j < 4; ++j) {
            int r = rr[j];
            int w = (r >= b1) + (r >= b2) + (r >= b3) + (r >= b4)
                  + (r >= b5) + (r >= b6) + (r >= b7);
            if (w == win) {
                int i = (i4 << 2) + j;
                float vv = __builtin_nontemporal_load(vals + i);
                int   cc = __builtin_nontemporal_load(cols + i);
                unsigned q = (unsigned)(vv * s + 0.5f);
                if (q > 16383u) q = 16383u;
                int pos = atomicAdd(&cursor[r], 1);
                cv[pos] = (q << COLBITS) | (unsigned)cc;
            }
        }
    }
    if ((blockIdx.x >> 3) == 0 && threadIdx.x == 0) {
        for (int i = nnz4 << 2; i < nnz; ++i) {
            int r = rows[i];
            int w = (r >= b1) + (r >= b2) + (r >= b3) + (r >= b4)
                  + (r >= b5) + (r >= b6) + (r >= b7);
            if (w == win) {
                unsigned q = (unsigned)(vals[i] * s + 0.5f);
                if (q > 16383u) q = 16383u;
                int pos = atomicAdd(&cursor[r], 1);
                cv[pos] = (q << COLBITS) | (unsigned)cols[i];
            }
        }
    }
}

// ===========================================================================
// gather SpMM over bf16 X, packed 4B records. out RMW and Yh store are
// non-temporal so the per-layer 96 MB of streaming traffic stops evicting
// Xh from L2 (gathers keep normal caching). cv loads stay on the proven
// scalar-K$ path (SGPR-hoisted bounds).
// ===========================================================================
template <int WRITE_NORM>
__global__ void spmm_csr_kernel(const int* __restrict__ row_ptr,
                                const unsigned* __restrict__ cv,
                                const unsigned short* __restrict__ Xh,
                                unsigned short* __restrict__ Yh,
                                float* __restrict__ out,
                                const int* __restrict__ vmax_bits,
                                float scale) {
    int wave = (blockIdx.x * blockDim.x + threadIdx.x) >> 6;
    if (wave >= NTOT) return;
    int lane = threadIdx.x & 63;
    float vmax = __int_as_float(__builtin_amdgcn_readfirstlane(*vmax_bits));
    float dq = vmax * (1.0f / QMAX);
    int start = __builtin_amdgcn_readfirstlane(row_ptr[wave]);
    int end   = __builtin_amdgcn_readfirstlane(row_ptr[wave + 1]);
    int n = end - start;
    const unsigned* p = cv + start;

    float acc = 0.0f;
    int k = 0;
    for (; k + 8 <= n; k += 8) {
        unsigned c0 = p[k + 0], c1 = p[k + 1], c2 = p[k + 2], c3 = p[k + 3];
        unsigned c4 = p[k + 4], c5 = p[k + 5], c6 = p[k + 6], c7 = p[k + 7];
        float x0 = bf2f(Xh[(size_t)(c0 & COLMASK) * EMB + lane]);
        float x1 = bf2f(Xh[(size_t)(c1 & COLMASK) * EMB + lane]);
        float x2 = bf2f(Xh[(size_t)(c2 & COLMASK) * EMB + lane]);
        float x3 = bf2f(Xh[(size_t)(c3 & COLMASK) * EMB + lane]);
        float x4 = bf2f(Xh[(size_t)(c4 & COLMASK) * EMB + lane]);
        float x5 = bf2f(Xh[(size_t)(c5 & COLMASK) * EMB + lane]);
        float x6 = bf2f(Xh[(size_t)(c6 & COLMASK) * EMB + lane]);
        float x7 = bf2f(Xh[(size_t)(c7 & COLMASK) * EMB + lane]);
        acc += (float)(c0 >> COLBITS) * dq * x0;
        acc += (float)(c1 >> COLBITS) * dq * x1;
        acc += (float)(c2 >> COLBITS) * dq * x2;
        acc += (float)(c3 >> COLBITS) * dq * x3;
        acc += (float)(c4 >> COLBITS) * dq * x4;
        acc += (float)(c5 >> COLBITS) * dq * x5;
        acc += (float)(c6 >> COLBITS) * dq * x6;
        acc += (float)(c7 >> COLBITS) * dq * x7;
    }
    for (; k + 4 <= n; k += 4) {
        unsigned c0 = p[k + 0], c1 = p[k + 1], c2 = p[k + 2], c3 = p[k + 3];
        float x0 = bf2f(Xh[(size_t)(c0 & COLMASK) * EMB + lane]);
        float x1 = bf2f(Xh[(size_t)(c1 & COLMASK) * EMB + lane]);
        float x2 = bf2f(Xh[(size_t)(c2 & COLMASK) * EMB + lane]);
        float x3 = bf2f(Xh[(size_t)(c3 & COLMASK) * EMB + lane]);
        acc += (float)(c0 >> COLBITS) * dq * x0;
        acc += (float)(c1 >> COLBITS) * dq * x1;
        acc += (float)(c2 >> COLBITS) * dq * x2;
        acc += (float)(c3 >> COLBITS) * dq * x3;
    }
    for (; k < n; ++k) {
        unsigned c0 = p[k];
        acc += (float)(c0 >> COLBITS) * dq
             * bf2f(Xh[(size_t)(c0 & COLMASK) * EMB + lane]);
    }

    size_t o = (size_t)wave * EMB + lane;
    float prev = __builtin_nontemporal_load(out + o);
    __builtin_nontemporal_store(prev + scale * acc, out + o);
    if (WRITE_NORM) {
        float ss = acc * acc;
        ss += __shfl_xor(ss, 1);
        ss += __shfl_xor(ss, 2);
        ss += __shfl_xor(ss, 4);
        ss += __shfl_xor(ss, 8);
        ss += __shfl_xor(ss, 16);
        ss += __shfl_xor(ss, 32);
        float inv = 1.0f / (sqrtf(ss) + EPS);
        __builtin_nontemporal_store(f2bf(acc * inv), Yh + o);
    }
}

// ===========================================================================
// Last-resort scatter path (round-1 proven kernels)
// ===========================================================================

__global__ void scale_copy_kernel(const float* __restrict__ src,
                                  float* __restrict__ dst, float a, int n4) {
    int stride = gridDim.x * blockDim.x;
    for (int i = blockIdx.x * blockDim.x + threadIdx.x; i < n4; i += stride) {
        float4 v = reinterpret_cast<const float4*>(src)[i];
        v.x *= a; v.y *= a; v.z *= a; v.w *= a;
        reinterpret_cast<float4*>(dst)[i] = v;
    }
}

__global__ void normalize_kernel(const float* __restrict__ src,
                                 float* __restrict__ dst, int nrows) {
    int tid = blockIdx.x * blockDim.x + threadIdx.x;
    int row = tid >> 4;
    if (row >= nrows) return;
    int l = tid & 15;
    float4 v = reinterpret_cast<const float4*>(src)[(size_t)row * 16 + l];
    float ss = v.x * v.x + v.y * v.y + v.z * v.z + v.w * v.w;
    ss += __shfl_xor(ss, 1);
    ss += __shfl_xor(ss, 2);
    ss += __shfl_xor(ss, 4);
    ss += __shfl_xor(ss, 8);
    float inv = 1.0f / (sqrtf(ss) + EPS);
    v.x *= inv; v.y *= inv; v.z *= inv; v.w *= inv;
    reinterpret_cast<float4*>(dst)[(size_t)row * 16 + l] = v;
}

__global__ void spmm_scatter_kernel(const int* __restrict__ rows,
                                    const int* __restrict__ cols,
                                    const float* __restrict__ vals,
                                    const float* __restrict__ x,
                                    float* __restrict__ y, int nnz) {
    int lane = threadIdx.x & 63;
    int wave = (blockIdx.x * blockDim.x + threadIdx.x) >> 6;
    int nw   = (gridDim.x * blockDim.x) >> 6;
    for (int i = wave; i < nnz; i += nw) {
        int   r = rows[i];
        int   c = cols[i];
        float v = vals[i];
        atomicAdd(&y[(size_t)r * EMB + lane], v * x[(size_t)c * EMB + lane]);
    }
}

__global__ void axpy_kernel(const float* __restrict__ x,
                            float* __restrict__ out, float a, int n4) {
    int stride = gridDim.x * blockDim.x;
    for (int i = blockIdx.x * blockDim.x + threadIdx.x; i < n4; i += stride) {
        float4 v = reinterpret_cast<const float4*>(x)[i];
        float4 o = reinterpret_cast<float4*>(out)[i];
        o.x += a * v.x; o.y += a * v.y; o.z += a * v.z; o.w += a * v.w;
        reinterpret_cast<float4*>(out)[i] = o;
    }
}

// ===========================================================================

extern "C" void kernel_launch(void* const* d_in, const int* in_sizes, int n_in,
                              void* d_out, int out_size, void* d_ws, size_t ws_size,
                              hipStream_t stream) {
    const float* user_emb = (const float*)d_in[0];
    const float* item_emb = (const float*)d_in[1];
    const int*   rows     = (const int*)d_in[2];
    const int*   cols     = (const int*)d_in[3];
    const float* vals     = (const float*)d_in[4];
    const int    nnz      = in_sizes[2];

    float* out = (float*)d_out;
    const int TOTAL = NTOT * EMB;                  // 9,600,000
    const float layer_scale = (1.0f - GAMMA) / NLAYERS;
    const int SPMM_BLOCKS = (NTOT * 64 + 255) / 256;

    // ---- layout: Xh | Yh | cv(4B) | row_ptr | cursor | chunks | rb | vmax --
    size_t need = (size_t)TOTAL * 2 * 2            // Xh, Yh (bf16)
                + (size_t)nnz * 4                  // packed cv
                + (size_t)(NTOT + 1) * 4
                + (size_t)NTOT * 4
                + (size_t)NCHUNKS * 4
                + 64                               // rb[9]
                + 64                               // vmax
                + 1024;

    if (ws_size >= need) {
        char* p = (char*)d_ws;
        unsigned short* Xh = (unsigned short*)p;  p += (size_t)TOTAL * 2;
        unsigned short* Yh = (unsigned short*)p;  p += (size_t)TOTAL * 2;
        unsigned* cv       = (unsigned*)p;        p += (size_t)nnz * 4;
        int*  row_ptr      = (int*)p;             p += (size_t)(NTOT + 1) * 4;
        int*  cursor       = (int*)p;             p += (size_t)NTOT * 4;
        int*  chunks       = (int*)p;             p += (size_t)NCHUNKS * 4;
        int*  rb           = (int*)p;             p += 64;
        int*  vmax_bits    = (int*)p;

        init_kernel<<<(NTOT * 16 + 255) / 256, 256, 0, stream>>>(
            user_emb, item_emb, Xh, out);

        hipMemsetAsync(vmax_bits, 0, 4, stream);
        vmax_kernel<<<1024, 256, 0, stream>>>(vals, vmax_bits, nnz);
        hipMemsetAsync(cursor, 0, (size_t)NTOT * 4, stream);   // counts
        hist4_kernel<<<2048, 256, 0, stream>>>(rows, cursor, nnz);
        scan_sums_kernel<<<NCHUNKS, SCAN_CHUNK, 0, stream>>>(cursor, chunks);
        scan_offsets_kernel<<<1, 64, 0, stream>>>(chunks, row_ptr);
        scan_write_kernel<<<NCHUNKS, SCAN_CHUNK, 0, stream>>>(cursor, chunks,
                                                              row_ptr, cursor);
        winbounds_kernel<<<1, 16, 0, stream>>>(row_ptr, rb, nnz);
        build_xcd_kernel<<<2048, 256, 0, stream>>>(rows, cols, vals, cursor,
                                                   rb, vmax_bits, cv, nnz);

        spmm_csr_kernel<1><<<SPMM_BLOCKS, 256, 0, stream>>>(
            row_ptr, cv, Xh, Yh, out, vmax_bits, layer_scale);
        spmm_csr_kernel<1><<<SPMM_BLOCKS, 256, 0, stream>>>(
            row_ptr, cv, Yh, Xh, out, vmax_bits, layer_scale);
        spmm_csr_kernel<0><<<SPMM_BLOCKS, 256, 0, stream>>>(
            row_ptr, cv, Xh, Yh, out, vmax_bits, layer_scale);
        return;
    }

    // ---- last resort: round-1 scatter path (needs 76.8 MB) ----
    float* A = (float*)d_ws;
    float* B = A + (size_t)TOTAL;
    const int T4 = TOTAL / 4;

    scale_copy_kernel<<<2048, 256, 0, stream>>>(user_emb, out, GAMMA,
                                                USER_NUM * EMB / 4);
    scale_copy_kernel<<<2048, 256, 0, stream>>>(item_emb, out + (size_t)USER_NUM * EMB,
                                                GAMMA, ITEM_NUM * EMB / 4);
    normalize_kernel<<<(USER_NUM * 16 + 255) / 256, 256, 0, stream>>>(
        user_emb, A, USER_NUM);
    normalize_kernel<<<(ITEM_NUM * 16 + 255) / 256, 256, 0, stream>>>(
        item_emb, A + (size_t)USER_NUM * EMB, ITEM_NUM);

    for (int layer = 0; layer < NLAYERS; ++layer) {
        if (layer > 0)
            normalize_kernel<<<(NTOT * 16 + 255) / 256, 256, 0, stream>>>(B, A, NTOT);
        hipMemsetAsync(B, 0, (size_t)TOTAL * sizeof(float), stream);
        spmm_scatter_kernel<<<8192, 256, 0, stream>>>(rows, cols, vals, A, B, nnz);
        axpy_kernel<<<2048, 256, 0, stream>>>(B, out, layer_scale, T4);
    }
}

// Round 13
// 1218.528 us; speedup vs baseline: 1.0673x; 1.0673x over previous
//
#include <hip/hip_runtime.h>

#define USER_NUM 100000
#define ITEM_NUM 50000
#define NTOT     (USER_NUM + ITEM_NUM)
#define EMB      64
#define GAMMA    0.5f
#define NLAYERS  3
#define EPS      1e-12f

#define SCAN_CHUNK 256
#define NCHUNKS    ((NTOT + SCAN_CHUNK - 1) / SCAN_CHUNK)   // 586

#define COLBITS  18
#define COLMASK  ((1u << COLBITS) - 1u)
#define QMAX     16382.0f

// ---- bf16 helpers (explicit RNE, bit-level) ----
__device__ __forceinline__ unsigned short f2bf(float f) {
    unsigned u = __float_as_uint(f);
    u = (u + 0x7FFFu + ((u >> 16) & 1u)) >> 16;
    return (unsigned short)u;
}
__device__ __forceinline__ float bf2f(unsigned short h) {
    return __uint_as_float((unsigned)h << 16);
}

// ===========================================================================
// init: Xh = bf16(normalize(concat(user,item))), out = GAMMA * concat(...)
// ===========================================================================
__global__ void init_kernel(const float* __restrict__ user_emb,
                            const float* __restrict__ item_emb,
                            unsigned short* __restrict__ Xh,
                            float* __restrict__ out) {
    int tid = blockIdx.x * blockDim.x + threadIdx.x;
    int row = tid >> 4;
    if (row >= NTOT) return;
    int l = tid & 15;
    const float* src = (row < USER_NUM)
        ? user_emb + (size_t)row * EMB
        : item_emb + (size_t)(row - USER_NUM) * EMB;
    float4 v = reinterpret_cast<const float4*>(src)[l];
    float4 o = v; o.x *= GAMMA; o.y *= GAMMA; o.z *= GAMMA; o.w *= GAMMA;
    reinterpret_cast<float4*>(out)[(size_t)row * 16 + l] = o;
    float ss = v.x * v.x + v.y * v.y + v.z * v.z + v.w * v.w;
    ss += __shfl_xor(ss, 1);
    ss += __shfl_xor(ss, 2);
    ss += __shfl_xor(ss, 4);
    ss += __shfl_xor(ss, 8);
    float inv = 1.0f / (sqrtf(ss) + EPS);
    ushort4 h;
    h.x = f2bf(v.x * inv); h.y = f2bf(v.y * inv);
    h.z = f2bf(v.z * inv); h.w = f2bf(v.w * inv);
    reinterpret_cast<ushort4*>(Xh)[(size_t)row * 16 + l] = h;
}

// ===========================================================================
// vmax reduction (positive floats)
// ===========================================================================
__global__ void vmax_kernel(const float* __restrict__ vals,
                            int* __restrict__ vmax_bits, int nnz) {
    int tid = blockIdx.x * blockDim.x + threadIdx.x;
    int stride = gridDim.x * blockDim.x;
    int nnz4 = nnz >> 2;
    float m = 0.0f;
    for (int i = tid; i < nnz4; i += stride) {
        float4 v = reinterpret_cast<const float4*>(vals)[i];
        m = fmaxf(m, fmaxf(fmaxf(v.x, v.y), fmaxf(v.z, v.w)));
    }
    if (tid == 0)
        for (int i = nnz4 << 2; i < nnz; ++i) m = fmaxf(m, vals[i]);
    m = fmaxf(m, __shfl_xor(m, 1));
    m = fmaxf(m, __shfl_xor(m, 2));
    m = fmaxf(m, __shfl_xor(m, 4));
    m = fmaxf(m, __shfl_xor(m, 8));
    m = fmaxf(m, __shfl_xor(m, 16));
    m = fmaxf(m, __shfl_xor(m, 32));
    if ((threadIdx.x & 63) == 0) atomicMax(vmax_bits, __float_as_int(m));
}

// ===========================================================================
// histogram (int4-vectorized index reads)
// ===========================================================================
__global__ void hist4_kernel(const int* __restrict__ rows,
                             int* __restrict__ counts, int nnz) {
    int tid = blockIdx.x * blockDim.x + threadIdx.x;
    int stride = gridDim.x * blockDim.x;
    int nnz4 = nnz >> 2;
    for (int i = tid; i < nnz4; i += stride) {
        int4 r4 = reinterpret_cast<const int4*>(rows)[i];
        atomicAdd(&counts[r4.x], 1);
        atomicAdd(&counts[r4.y], 1);
        atomicAdd(&counts[r4.z], 1);
        atomicAdd(&counts[r4.w], 1);
    }
    if (tid == 0)
        for (int i = nnz4 << 2; i < nnz; ++i) atomicAdd(&counts[rows[i]], 1);
}

// ===========================================================================
// 3-step exclusive scan of per-row counts -> row_ptr (and cursor copy)
// ===========================================================================
__global__ void scan_sums_kernel(const int* __restrict__ counts,
                                 int* __restrict__ chunk_sums) {
    __shared__ int sdata[SCAN_CHUNK];
    int idx = blockIdx.x * SCAN_CHUNK + threadIdx.x;
    int v = (idx < NTOT) ? counts[idx] : 0;
    sdata[threadIdx.x] = v;
    __syncthreads();
    for (int off = SCAN_CHUNK / 2; off > 0; off >>= 1) {
        if (threadIdx.x < off) sdata[threadIdx.x] += sdata[threadIdx.x + off];
        __syncthreads();
    }
    if (threadIdx.x == 0) chunk_sums[blockIdx.x] = sdata[0];
}

__global__ void scan_offsets_kernel(int* __restrict__ chunk_sums,
                                    int* __restrict__ row_ptr) {
    if (threadIdx.x == 0 && blockIdx.x == 0) {
        int running = 0;
        for (int b = 0; b < NCHUNKS; ++b) {
            int t = chunk_sums[b];
            chunk_sums[b] = running;
            running += t;
        }
        row_ptr[NTOT] = running;
    }
}

__global__ void scan_write_kernel(const int* __restrict__ counts,
                                  const int* __restrict__ chunk_sums,
                                  int* __restrict__ row_ptr,
                                  int* __restrict__ cursor) {
    __shared__ int temp[SCAN_CHUNK];
    int idx = blockIdx.x * SCAN_CHUNK + threadIdx.x;
    int v = (idx < NTOT) ? counts[idx] : 0;
    temp[threadIdx.x] = v;
    __syncthreads();
    for (int off = 1; off < SCAN_CHUNK; off <<= 1) {
        int t = (threadIdx.x >= off) ? temp[threadIdx.x - off] : 0;
        __syncthreads();
        temp[threadIdx.x] += t;
        __syncthreads();
    }
    if (idx < NTOT) {
        int excl = temp[threadIdx.x] - v + chunk_sums[blockIdx.x];
        row_ptr[idx] = excl;
        cursor[idx]  = excl;
    }
}

// ===========================================================================
// window boundaries: rb[w] = smallest row with row_ptr[row] >= w*nnz/8.
// ===========================================================================
__global__ void winbounds_kernel(const int* __restrict__ row_ptr,
                                 int* __restrict__ rb, int nnz) {
    int w = threadIdx.x;
    if (w > 8) return;
    if (w == 0) { rb[0] = 0; return; }
    if (w == 8) { rb[8] = NTOT; return; }
    int target = (int)(((long long)nnz * w) >> 3);
    int lo = 0, hi = NTOT;
    while (lo < hi) {
        int mid = (lo + hi) >> 1;
        if (row_ptr[mid] < target) lo = mid + 1; else hi = mid;
    }
    rb[w] = lo;
}

// ===========================================================================
// XCD-cohort CSR build, 4-byte packed records (round-10 proven form; nt
// hints removed permanently — round-12 showed they regress both sides).
// ~400 µs / 451 MB writes is accepted as this phase's structural floor.
// ===========================================================================
__global__ void build_xcd_kernel(const int* __restrict__ rows,
                                 const int* __restrict__ cols,
                                 const float* __restrict__ vals,
                                 int* __restrict__ cursor,
                                 const int* __restrict__ rb,
                                 const int* __restrict__ vmax_bits,
                                 unsigned* __restrict__ cv, int nnz) {
    __shared__ int srb[8];
    if (threadIdx.x < 8) srb[threadIdx.x] = rb[threadIdx.x];
    __syncthreads();
    const int b1 = srb[1], b2 = srb[2], b3 = srb[3], b4 = srb[4];
    const int b5 = srb[5], b6 = srb[6], b7 = srb[7];
    const int win = blockIdx.x & 7;
    float vmax = __int_as_float(__builtin_amdgcn_readfirstlane(*vmax_bits));
    float s = (vmax > 0.0f) ? (QMAX / vmax) : 0.0f;

    int i4      = (blockIdx.x >> 3) * blockDim.x + threadIdx.x;
    int stride4 = (gridDim.x >> 3) * blockDim.x;
    int nnz4    = nnz >> 2;
    for (; i4 < nnz4; i4 += stride4) {
        int4 r4 = reinterpret_cast<const int4*>(rows)[i4];
        int rr[4] = {r4.x, r4.y, r4.z, r4.w};
#pragma unroll
        for (int j = 0; j < 4; ++j) {
            int r = rr[j];
            int w = (r >= b1) + (r >= b2) + (r >= b3) + (r >= b4)
                  + (r >= b5) + (r >= b6) + (r >= b7);
            if (w == win) {
                int i = (i4 << 2) + j;
                unsigned q = (unsigned)(vals[i] * s + 0.5f);
                if (q > 16383u) q = 16383u;
                int pos = atomicAdd(&cursor[r], 1);
                cv[pos] = (q << COLBITS) | (unsigned)cols[i];
            }
        }
    }
    if ((blockIdx.x >> 3) == 0 && threadIdx.x == 0) {
        for (int i = nnz4 << 2; i < nnz; ++i) {
            int r = rows[i];
            int w = (r >= b1) + (r >= b2) + (r >= b3) + (r >= b4)
                  + (r >= b5) + (r >= b6) + (r >= b7);
            if (w == win) {
                unsigned q = (unsigned)(vals[i] * s + 0.5f);
                if (q > 16383u) q = 16383u;
                int pos = atomicAdd(&cursor[r], 1);
                cv[pos] = (q << COLBITS) | (unsigned)cols[i];
            }
        }
    }
}

// ===========================================================================
// gather SpMM over bf16 X, packed 4B records: one wave per row, lane = dim.
// 16-deep gather batches (2x round-10's 8) to double per-wave memory-level
// parallelism — spmm is gather-latency bound, not bandwidth bound.
// Row bounds + dequant scale hoisted to SGPRs via readfirstlane.
// ===========================================================================
template <int WRITE_NORM>
__global__ void spmm_csr_kernel(const int* __restrict__ row_ptr,
                                const unsigned* __restrict__ cv,
                                const unsigned short* __restrict__ Xh,
                                unsigned short* __restrict__ Yh,
                                float* __restrict__ out,
                                const int* __restrict__ vmax_bits,
                                float scale) {
    int wave = (blockIdx.x * blockDim.x + threadIdx.x) >> 6;
    if (wave >= NTOT) return;
    int lane = threadIdx.x & 63;
    float vmax = __int_as_float(__builtin_amdgcn_readfirstlane(*vmax_bits));
    float dq = vmax * (1.0f / QMAX);
    int start = __builtin_amdgcn_readfirstlane(row_ptr[wave]);
    int end   = __builtin_amdgcn_readfirstlane(row_ptr[wave + 1]);
    int n = end - start;
    const unsigned* p = cv + start;

    float acc = 0.0f;
    int k = 0;
    for (; k + 16 <= n; k += 16) {
        unsigned c0 = p[k + 0],  c1 = p[k + 1],  c2 = p[k + 2],  c3 = p[k + 3];
        unsigned c4 = p[k + 4],  c5 = p[k + 5],  c6 = p[k + 6],  c7 = p[k + 7];
        unsigned c8 = p[k + 8],  c9 = p[k + 9],  ca = p[k + 10], cb = p[k + 11];
        unsigned cc = p[k + 12], cd = p[k + 13], ce = p[k + 14], cf = p[k + 15];
        float x0 = bf2f(Xh[(size_t)(c0 & COLMASK) * EMB + lane]);
        float x1 = bf2f(Xh[(size_t)(c1 & COLMASK) * EMB + lane]);
        float x2 = bf2f(Xh[(size_t)(c2 & COLMASK) * EMB + lane]);
        float x3 = bf2f(Xh[(size_t)(c3 & COLMASK) * EMB + lane]);
        float x4 = bf2f(Xh[(size_t)(c4 & COLMASK) * EMB + lane]);
        float x5 = bf2f(Xh[(size_t)(c5 & COLMASK) * EMB + lane]);
        float x6 = bf2f(Xh[(size_t)(c6 & COLMASK) * EMB + lane]);
        float x7 = bf2f(Xh[(size_t)(c7 & COLMASK) * EMB + lane]);
        float x8 = bf2f(Xh[(size_t)(c8 & COLMASK) * EMB + lane]);
        float x9 = bf2f(Xh[(size_t)(c9 & COLMASK) * EMB + lane]);
        float xa = bf2f(Xh[(size_t)(ca & COLMASK) * EMB + lane]);
        float xb = bf2f(Xh[(size_t)(cb & COLMASK) * EMB + lane]);
        float xc = bf2f(Xh[(size_t)(cc & COLMASK) * EMB + lane]);
        float xd = bf2f(Xh[(size_t)(cd & COLMASK) * EMB + lane]);
        float xe = bf2f(Xh[(size_t)(ce & COLMASK) * EMB + lane]);
        float xf = bf2f(Xh[(size_t)(cf & COLMASK) * EMB + lane]);
        acc += (float)(c0 >> COLBITS) * dq * x0;
        acc += (float)(c1 >> COLBITS) * dq * x1;
        acc += (float)(c2 >> COLBITS) * dq * x2;
        acc += (float)(c3 >> COLBITS) * dq * x3;
        acc += (float)(c4 >> COLBITS) * dq * x4;
        acc += (float)(c5 >> COLBITS) * dq * x5;
        acc += (float)(c6 >> COLBITS) * dq * x6;
        acc += (float)(c7 >> COLBITS) * dq * x7;
        acc += (float)(c8 >> COLBITS) * dq * x8;
        acc += (float)(c9 >> COLBITS) * dq * x9;
        acc += (float)(ca >> COLBITS) * dq * xa;
        acc += (float)(cb >> COLBITS) * dq * xb;
        acc += (float)(cc >> COLBITS) * dq * xc;
        acc += (float)(cd >> COLBITS) * dq * xd;
        acc += (float)(ce >> COLBITS) * dq * xe;
        acc += (float)(cf >> COLBITS) * dq * xf;
    }
    for (; k + 8 <= n; k += 8) {
        unsigned c0 = p[k + 0], c1 = p[k + 1], c2 = p[k + 2], c3 = p[k + 3];
        unsigned c4 = p[k + 4], c5 = p[k + 5], c6 = p[k + 6], c7 = p[k + 7];
        float x0 = bf2f(Xh[(size_t)(c0 & COLMASK) * EMB + lane]);
        float x1 = bf2f(Xh[(size_t)(c1 & COLMASK) * EMB + lane]);
        float x2 = bf2f(Xh[(size_t)(c2 & COLMASK) * EMB + lane]);
        float x3 = bf2f(Xh[(size_t)(c3 & COLMASK) * EMB + lane]);
        float x4 = bf2f(Xh[(size_t)(c4 & COLMASK) * EMB + lane]);
        float x5 = bf2f(Xh[(size_t)(c5 & COLMASK) * EMB + lane]);
        float x6 = bf2f(Xh[(size_t)(c6 & COLMASK) * EMB + lane]);
        float x7 = bf2f(Xh[(size_t)(c7 & COLMASK) * EMB + lane]);
        acc += (float)(c0 >> COLBITS) * dq * x0;
        acc += (float)(c1 >> COLBITS) * dq * x1;
        acc += (float)(c2 >> COLBITS) * dq * x2;
        acc += (float)(c3 >> COLBITS) * dq * x3;
        acc += (float)(c4 >> COLBITS) * dq * x4;
        acc += (float)(c5 >> COLBITS) * dq * x5;
        acc += (float)(c6 >> COLBITS) * dq * x6;
        acc += (float)(c7 >> COLBITS) * dq * x7;
    }
    for (; k + 4 <= n; k += 4) {
        unsigned c0 = p[k + 0], c1 = p[k + 1], c2 = p[k + 2], c3 = p[k + 3];
        float x0 = bf2f(Xh[(size_t)(c0 & COLMASK) * EMB + lane]);
        float x1 = bf2f(Xh[(size_t)(c1 & COLMASK) * EMB + lane]);
        float x2 = bf2f(Xh[(size_t)(c2 & COLMASK) * EMB + lane]);
        float x3 = bf2f(Xh[(size_t)(c3 & COLMASK) * EMB + lane]);
        acc += (float)(c0 >> COLBITS) * dq * x0;
        acc += (float)(c1 >> COLBITS) * dq * x1;
        acc += (float)(c2 >> COLBITS) * dq * x2;
        acc += (float)(c3 >> COLBITS) * dq * x3;
    }
    for (; k < n; ++k) {
        unsigned c0 = p[k];
        acc += (float)(c0 >> COLBITS) * dq
             * bf2f(Xh[(size_t)(c0 & COLMASK) * EMB + lane]);
    }

    size_t o = (size_t)wave * EMB + lane;
    out[o] += scale * acc;
    if (WRITE_NORM) {
        float ss = acc * acc;
        ss += __shfl_xor(ss, 1);
        ss += __shfl_xor(ss, 2);
        ss += __shfl_xor(ss, 4);
        ss += __shfl_xor(ss, 8);
        ss += __shfl_xor(ss, 16);
        ss += __shfl_xor(ss, 32);
        float inv = 1.0f / (sqrtf(ss) + EPS);
        Yh[o] = f2bf(acc * inv);
    }
}

// ===========================================================================
// Last-resort scatter path (round-1 proven kernels)
// ===========================================================================

__global__ void scale_copy_kernel(const float* __restrict__ src,
                                  float* __restrict__ dst, float a, int n4) {
    int stride = gridDim.x * blockDim.x;
    for (int i = blockIdx.x * blockDim.x + threadIdx.x; i < n4; i += stride) {
        float4 v = reinterpret_cast<const float4*>(src)[i];
        v.x *= a; v.y *= a; v.z *= a; v.w *= a;
        reinterpret_cast<float4*>(dst)[i] = v;
    }
}

__global__ void normalize_kernel(const float* __restrict__ src,
                                 float* __restrict__ dst, int nrows) {
    int tid = blockIdx.x * blockDim.x + threadIdx.x;
    int row = tid >> 4;
    if (row >= nrows) return;
    int l = tid & 15;
    float4 v = reinterpret_cast<const float4*>(src)[(size_t)row * 16 + l];
    float ss = v.x * v.x + v.y * v.y + v.z * v.z + v.w * v.w;
    ss += __shfl_xor(ss, 1);
    ss += __shfl_xor(ss, 2);
    ss += __shfl_xor(ss, 4);
    ss += __shfl_xor(ss, 8);
    float inv = 1.0f / (sqrtf(ss) + EPS);
    v.x *= inv; v.y *= inv; v.z *= inv; v.w *= inv;
    reinterpret_cast<float4*>(dst)[(size_t)row * 16 + l] = v;
}

__global__ void spmm_scatter_kernel(const int* __restrict__ rows,
                                    const int* __restrict__ cols,
                                    const float* __restrict__ vals,
                                    const float* __restrict__ x,
                                    float* __restrict__ y, int nnz) {
    int lane = threadIdx.x & 63;
    int wave = (blockIdx.x * blockDim.x + threadIdx.x) >> 6;
    int nw   = (gridDim.x * blockDim.x) >> 6;
    for (int i = wave; i < nnz; i += nw) {
        int   r = rows[i];
        int   c = cols[i];
        float v = vals[i];
        atomicAdd(&y[(size_t)r * EMB + lane], v * x[(size_t)c * EMB + lane]);
    }
}

__global__ void axpy_kernel(const float* __restrict__ x,
                            float* __restrict__ out, float a, int n4) {
    int stride = gridDim.x * blockDim.x;
    for (int i = blockIdx.x * blockDim.x + threadIdx.x; i < n4; i += stride) {
        float4 v = reinterpret_cast<const float4*>(x)[i];
        float4 o = reinterpret_cast<float4*>(out)[i];
        o.x += a * v.x; o.y += a * v.y; o.z += a * v.z; o.w += a * v.w;
        reinterpret_cast<float4*>(out)[i] = o;
    }
}

// ===========================================================================

extern "C" void kernel_launch(void* const* d_in, const int* in_sizes, int n_in,
                              void* d_out, int out_size, void* d_ws, size_t ws_size,
                              hipStream_t stream) {
    const float* user_emb = (const float*)d_in[0];
    const float* item_emb = (const float*)d_in[1];
    const int*   rows     = (const int*)d_in[2];
    const int*   cols     = (const int*)d_in[3];
    const float* vals     = (const float*)d_in[4];
    const int    nnz      = in_sizes[2];

    float* out = (float*)d_out;
    const int TOTAL = NTOT * EMB;                  // 9,600,000
    const float layer_scale = (1.0f - GAMMA) / NLAYERS;
    const int SPMM_BLOCKS = (NTOT * 64 + 255) / 256;

    // ---- layout: Xh | Yh | cv(4B) | row_ptr | cursor | chunks | rb | vmax --
    size_t need = (size_t)TOTAL * 2 * 2            // Xh, Yh (bf16)
                + (size_t)nnz * 4                  // packed cv
                + (size_t)(NTOT + 1) * 4
                + (size_t)NTOT * 4
                + (size_t)NCHUNKS * 4
                + 64                               // rb[9]
                + 64                               // vmax
                + 1024;

    if (ws_size >= need) {
        char* p = (char*)d_ws;
        unsigned short* Xh = (unsigned short*)p;  p += (size_t)TOTAL * 2;
        unsigned short* Yh = (unsigned short*)p;  p += (size_t)TOTAL * 2;
        unsigned* cv       = (unsigned*)p;        p += (size_t)nnz * 4;
        int*  row_ptr      = (int*)p;             p += (size_t)(NTOT + 1) * 4;
        int*  cursor       = (int*)p;             p += (size_t)NTOT * 4;
        int*  chunks       = (int*)p;             p += (size_t)NCHUNKS * 4;
        int*  rb           = (int*)p;             p += 64;
        int*  vmax_bits    = (int*)p;

        init_kernel<<<(NTOT * 16 + 255) / 256, 256, 0, stream>>>(
            user_emb, item_emb, Xh, out);

        hipMemsetAsync(vmax_bits, 0, 4, stream);
        vmax_kernel<<<1024, 256, 0, stream>>>(vals, vmax_bits, nnz);
        hipMemsetAsync(cursor, 0, (size_t)NTOT * 4, stream);   // counts
        hist4_kernel<<<2048, 256, 0, stream>>>(rows, cursor, nnz);
        scan_sums_kernel<<<NCHUNKS, SCAN_CHUNK, 0, stream>>>(cursor, chunks);
        scan_offsets_kernel<<<1, 64, 0, stream>>>(chunks, row_ptr);
        scan_write_kernel<<<NCHUNKS, SCAN_CHUNK, 0, stream>>>(cursor, chunks,
                                                              row_ptr, cursor);
        winbounds_kernel<<<1, 16, 0, stream>>>(row_ptr, rb, nnz);
        build_xcd_kernel<<<2048, 256, 0, stream>>>(rows, cols, vals, cursor,
                                                   rb, vmax_bits, cv, nnz);

        spmm_csr_kernel<1><<<SPMM_BLOCKS, 256, 0, stream>>>(
            row_ptr, cv, Xh, Yh, out, vmax_bits, layer_scale);
        spmm_csr_kernel<1><<<SPMM_BLOCKS, 256, 0, stream>>>(
            row_ptr, cv, Yh, Xh, out, vmax_bits, layer_scale);
        spmm_csr_kernel<0><<<SPMM_BLOCKS, 256, 0, stream>>>(
            row_ptr, cv, Xh, Yh, out, vmax_bits, layer_scale);
        return;
    }

    // ---- last resort: round-1 scatter path (needs 76.8 MB) ----
    float* A = (float*)d_ws;
    float* B = A + (size_t)TOTAL;
    const int T4 = TOTAL / 4;

    scale_copy_kernel<<<2048, 256, 0, stream>>>(user_emb, out, GAMMA,
                                                USER_NUM * EMB / 4);
    scale_copy_kernel<<<2048, 256, 0, stream>>>(item_emb, out + (size_t)USER_NUM * EMB,
                                                GAMMA, ITEM_NUM * EMB / 4);
    normalize_kernel<<<(USER_NUM * 16 + 255) / 256, 256, 0, stream>>>(
        user_emb, A, USER_NUM);
    normalize_kernel<<<(ITEM_NUM * 16 + 255) / 256, 256, 0, stream>>>(
        item_emb, A + (size_t)USER_NUM * EMB, ITEM_NUM);

    for (int layer = 0; layer < NLAYERS; ++layer) {
        if (layer > 0)
            normalize_kernel<<<(NTOT * 16 + 255) / 256, 256, 0, stream>>>(B, A, NTOT);
        hipMemsetAsync(B, 0, (size_t)TOTAL * sizeof(float), stream);
        spmm_scatter_kernel<<<8192, 256, 0, stream>>>(rows, cols, vals, A, B, nnz);
        axpy_kernel<<<2048, 256, 0, stream>>>(B, out, layer_scale, T4);
    }
}